// Round 10
// baseline (661.821 us; speedup 1.0000x reference)
//
#include <hip/hip_runtime.h>
#include <hip/hip_bf16.h>
#include <math.h>

// ---------------------------------------------------------------------------
// Round 10: discriminating experiment on the r8 skeleton (r9 packed math
// REVERTED — it regressed with identical VALUBusy). Changes vs r8:
//   - RPB 16->8, grid 2048, __launch_bounds__(128,4): target 8 blocks/CU =
//     4 waves/SIMD from >=2 INDEPENDENT (non-barrier-coupled) blocks.
//   - LDS 28.7KB -> ~16KB: hpL halves (8 rows), hshT unioned with vs.
//   - Y2 LDS byte-offsets precomputed outside the loop; per-tile buffer
//     toggle is a single XOR 4096 (removes per-tile address chains).
//   - tail masking: 408 samples = 25.5 16-sample tiles -> 26 tiles, lanes
//     with slocal>=408 clamped on reads / guarded on writes.
// Theory split: latency-bound -> 85-100 us; VALU-pipe-saturated -> neutral
// with VALUBusy rising ~2x. Numerics chain unchanged (absmax 0.125).
// ---------------------------------------------------------------------------

#define B_N    16384
#define KQ     51
#define HD     128
#define IND    64
#define BLK    128               // 2 waves = 1 pair
#define GRID   2048              // 16384/8 rows
#define RPB    8                 // b-rows per block(pair)
#define SPB    (RPB * KQ)        // 408 samples per pair
#define NT16   26                // ceil(408/16) tiles
#define HPITCH 12                // hshT pitch (48B rows, 16B-aligned)

typedef __attribute__((ext_vector_type(8))) short short8;
typedef __attribute__((ext_vector_type(4))) float f32x4;

union S8U { short8 s8; unsigned u[4]; };

__device__ __forceinline__ unsigned short f2bf(float f) {
    __hip_bfloat16 t = __float2bfloat16(f);
    return *reinterpret_cast<unsigned short*>(&t);
}

#if defined(__gfx950__) && defined(__has_builtin)
#if __has_builtin(__builtin_amdgcn_cvt_pk_bf16_f32)
#define HAVE_PK_BF16 1
#endif
#endif

__device__ __forceinline__ unsigned pk_bf16(float lo, float hi) {
#ifdef HAVE_PK_BF16
    typedef __attribute__((ext_vector_type(2))) __bf16 bfv2;
    bfv2 r = __builtin_amdgcn_cvt_pk_bf16_f32(lo, hi);
    return *reinterpret_cast<unsigned*>(&r);
#else
    return (unsigned)f2bf(lo) | ((unsigned)f2bf(hi) << 16);
#endif
}

__launch_bounds__(BLK, 4)
__global__ void umnn_fused(const float* __restrict__ x,  const float* __restrict__ h,
                           const float* __restrict__ W1, const float* __restrict__ b1,
                           const float* __restrict__ W2, const float* __restrict__ b2,
                           const float* __restrict__ W3, const float* __restrict__ b3,
                           const float* __restrict__ W4, const float* __restrict__ b4,
                           float* __restrict__ out)
{
    __shared__ __align__(16) float hpL[RPB * HD];       // 4 KB block hpart
    __shared__ __align__(16) char  y2b[2 * 4096];       // 8 KB Y2 double-buffer
    __shared__ __align__(16) float uSh[2 * SPB];        // 3.3 KB: hshT then vs
    __shared__ float xL[RPB];
    __shared__ float sSteps[KQ], sCcw[KQ];
    __shared__ float red2[2];

    float* hshT = uSh;                                  // 63*12=756 (pre-B2)
    float (*vs)[SPB] = (float(*)[SPB])uSh;              // 2*408 (post-B2)

    const int tid  = threadIdx.x;
    const int w    = tid >> 6;
    const int lane = tid & 63;
    const int q    = lane >> 4;
    const int lm   = lane & 15;
    const int swz  = lm & 7;
    const int rowBase = blockIdx.x * RPB;

    // ---- CC tables (validated r4 formula) ----
    if (tid < KQ) {
        const int j = tid;
        const float pi50 = 0.06283185307179586f;
        sSteps[j] = __cosf((float)j * pi50);
        float s = 0.0f;
        for (int i = 0; i <= 50; i += 2) {
            float Wi = (i == 0) ? 1.0f : 2.0f / (1.0f - (float)(i * i));
            float lam;
            if (j == 0) lam = 0.5f;
            else {
                int mp = (i * j) % 100;
                lam = __cosf((float)mp * pi50);
                if (j == 50) lam *= 0.5f;
            }
            s += (lam * 0.04f) * Wi;
        }
        sCcw[j] = s;
    }
    // ---- xmax scan (x: 64 KB, cache-resident) ----
    {
        const f32x4* x4 = (const f32x4*)x;
        float mx = -1e30f;
        for (int i = tid; i < B_N / 4; i += BLK) {
            f32x4 v = x4[i];
            mx = fmaxf(fmaxf(mx, fmaxf(v[0], v[1])), fmaxf(v[2], v[3]));
        }
        #pragma unroll
        for (int d = 32; d > 0; d >>= 1) mx = fmaxf(mx, __shfl_xor(mx, d));
        if (lane == 0) red2[w] = mx;
    }
    // ---- stage h^T (8 rows); init xL ----
    for (int i = tid; i < RPB * 63; i += BLK) {
        int r = i / 63, d = i - r * 63;
        hshT[d * HPITCH + r] = h[rowBase * 63 + i];
    }
    if (tid < RPB) xL[tid] = x[rowBase + tid];
    __syncthreads();                                   // B1

    const float xmax = fmaxf(red2[0], red2[1]) + 10.0f;

    // ---- block hpart: thread tid = feature n, 8 row-accumulators ----
    {
        const int n = tid;
        float acc[RPB];
        const float b1v = b1[n];
        #pragma unroll
        for (int r = 0; r < RPB; ++r) acc[r] = b1v;
        const float* wr = W1 + n * IND + 1;
        #pragma unroll 1
        for (int d = 0; d < IND - 1; ++d) {
            float wv = wr[d];
            const float* ht = hshT + d * HPITCH;
            #pragma unroll
            for (int rc = 0; rc < RPB / 4; ++rc) {
                f32x4 hv = *(const f32x4*)(ht + rc * 4);
                acc[rc * 4 + 0] = fmaf(wv, hv[0], acc[rc * 4 + 0]);
                acc[rc * 4 + 1] = fmaf(wv, hv[1], acc[rc * 4 + 1]);
                acc[rc * 4 + 2] = fmaf(wv, hv[2], acc[rc * 4 + 2]);
                acc[rc * 4 + 3] = fmaf(wv, hv[3], acc[rc * 4 + 3]);
            }
        }
        #pragma unroll
        for (int r = 0; r < RPB; ++r) hpL[r * HD + n] = acc[r];
    }

    // ---- wave-resident weights/biases: this wave's 64 output features ----
    float w1x[32];
    #pragma unroll
    for (int kk = 0; kk < 4; ++kk)
        #pragma unroll
        for (int j = 0; j < 8; ++j)
            w1x[kk * 8 + j] = W1[(kk * 32 + q * 8 + j) * IND];

    short8 W2A[4][4], W3A[4][4];
    f32x4  b2c[4], b3c[4], W4c[4];
    #pragma unroll
    for (int nt = 0; nt < 4; ++nt) {
        const int ntg = w * 4 + nt;
        #pragma unroll
        for (int kk = 0; kk < 4; ++kk) {
            const float* p2 = W2 + (ntg * 16 + lm) * HD + kk * 32 + q * 8;
            const float* p3 = W3 + (ntg * 16 + lm) * HD + kk * 32 + q * 8;
            S8U a2, a3;
            #pragma unroll
            for (int j = 0; j < 4; ++j) {
                a2.u[j] = pk_bf16(p2[2 * j], p2[2 * j + 1]);
                a3.u[j] = pk_bf16(p3[2 * j], p3[2 * j + 1]);
            }
            W2A[nt][kk] = a2.s8; W3A[nt][kk] = a3.s8;
        }
        b2c[nt] = *(const f32x4*)(b2 + ntg * 16 + q * 4);
        b3c[nt] = *(const f32x4*)(b3 + ntg * 16 + q * 4);
        W4c[nt] = *(const f32x4*)(W4 + ntg * 16 + q * 4);
    }
    const float b4v = b4[0];

    // ---- precomputed LDS byte offsets (tile-invariant; buf toggles ^4096) ----
    int wOff[4], rOff[4];
    #pragma unroll
    for (int nt = 0; nt < 4; ++nt) {
        const int cch = 2 * (w * 4 + nt) + (q >> 1);
        wOff[nt] = lm * 256 + ((cch ^ swz) << 4) + ((q & 1) << 3);
        rOff[nt] = lm * 256 + (((nt * 4 + q) ^ swz) << 4);   // nt reused as kk
    }
    __syncthreads();                                   // B2 (hpL ready, hshT dead)

    // ================= pair tile loop: 1 barrier per tile =================
    #pragma unroll 1
    for (int tt = 0; tt < NT16; ++tt) {
        char* buf = y2b + ((tt & 1) << 12);

        // ---- per-lane sample indices (block-local) ----
        const int slocal = tt * 16 + lm;
        const int rl  = (int)((unsigned)slocal / KQ);        // 0..8
        const int k   = slocal - rl * KQ;
        const int rlc = (rl < RPB) ? rl : RPB - 1;           // clamp tail
        const float x0 = xL[rlc];
        const float X  = fmaf((xmax - x0) * 0.5f, sSteps[k] + 1.0f, x0);

        // ---- Y1 B-frags in registers (r8 scalar math) ----
        short8 Y1[4];
        #pragma unroll
        for (int kk = 0; kk < 4; ++kk) {
            const float* hp = hpL + rlc * HD + kk * 32 + q * 8;
            f32x4 ha = *(const f32x4*)hp;
            f32x4 hb = *(const f32x4*)(hp + 4);
            S8U u;
            u.u[0] = pk_bf16(fmaxf(fmaf(X, w1x[kk*8+0], ha[0]), 0.f),
                             fmaxf(fmaf(X, w1x[kk*8+1], ha[1]), 0.f));
            u.u[1] = pk_bf16(fmaxf(fmaf(X, w1x[kk*8+2], ha[2]), 0.f),
                             fmaxf(fmaf(X, w1x[kk*8+3], ha[3]), 0.f));
            u.u[2] = pk_bf16(fmaxf(fmaf(X, w1x[kk*8+4], hb[0]), 0.f),
                             fmaxf(fmaf(X, w1x[kk*8+5], hb[1]), 0.f));
            u.u[3] = pk_bf16(fmaxf(fmaf(X, w1x[kk*8+6], hb[2]), 0.f),
                             fmaxf(fmaf(X, w1x[kk*8+7], hb[3]), 0.f));
            Y1[kk] = u.s8;
        }

        // ---- layer 2: 16 MFMA (this wave's 64 features) ----
        f32x4 C[4];
        #pragma unroll
        for (int nt = 0; nt < 4; ++nt) C[nt] = b2c[nt];
        #pragma unroll
        for (int kk = 0; kk < 4; ++kk)
            #pragma unroll
            for (int nt = 0; nt < 4; ++nt)
                C[nt] = __builtin_amdgcn_mfma_f32_16x16x32_bf16(W2A[nt][kk], Y1[kk], C[nt], 0, 0, 0);

        // ---- Y2 half -> shared double-buffer ----
        #pragma unroll
        for (int nt = 0; nt < 4; ++nt) {
            unsigned lo = pk_bf16(fmaxf(C[nt][0], 0.f), fmaxf(C[nt][1], 0.f));
            unsigned hi = pk_bf16(fmaxf(C[nt][2], 0.f), fmaxf(C[nt][3], 0.f));
            *(int2*)(buf + wOff[nt]) = make_int2((int)lo, (int)hi);
        }
        __syncthreads();                               // Y2 tile complete

        // ---- layer 3: full-K B-frags from shared Y2 ----
        short8 Y2[4];
        #pragma unroll
        for (int kk = 0; kk < 4; ++kk)
            Y2[kk] = *(const short8*)(buf + rOff[kk]);
        #pragma unroll
        for (int nt = 0; nt < 4; ++nt) C[nt] = b3c[nt];
        #pragma unroll
        for (int kk = 0; kk < 4; ++kk)
            #pragma unroll
            for (int nt = 0; nt < 4; ++nt)
                C[nt] = __builtin_amdgcn_mfma_f32_16x16x32_bf16(W3A[nt][kk], Y2[kk], C[nt], 0, 0, 0);

        // ---- layer 4 partial (this wave's 64 features): q-reduce, store ----
        float p = 0.f;
        #pragma unroll
        for (int nt = 0; nt < 4; ++nt) {
            p = fmaf(fmaxf(C[nt][0], 0.f), W4c[nt][0], p);
            p = fmaf(fmaxf(C[nt][1], 0.f), W4c[nt][1], p);
            p = fmaf(fmaxf(C[nt][2], 0.f), W4c[nt][2], p);
            p = fmaf(fmaxf(C[nt][3], 0.f), W4c[nt][3], p);
        }
        p += __shfl_xor(p, 16);
        p += __shfl_xor(p, 32);
        if (lane < 16 && rl < RPB) vs[w][slocal] = p;
    }
    __syncthreads();                                   // vs complete

    // ---- deferred epilogue (wave 0): elu+ccw+row-reduce, plain stores ----
    if (w == 0) {
        const int r   = lane >> 2;          // 0..15, valid < RPB
        const int sub = lane & 3;
        if (r < RPB) {
            float a = 0.f;
            #pragma unroll 1
            for (int j = 0; j < 13; ++j) {
                int kq = sub + 4 * j;
                if (kq < KQ) {
                    int sl = r * KQ + kq;
                    float y4 = vs[0][sl] + vs[1][sl] + b4v;
                    float f  = (y4 > 0.f) ? (y4 + 1.f) : __expf(y4);
                    a = fmaf(f, sCcw[kq], a);
                }
            }
            a += __shfl_xor(a, 1);
            a += __shfl_xor(a, 2);
            if (sub == 0)
                out[rowBase + r] = a * (xmax - xL[r]) * 0.5f;
        }
    }
}

// ---------------------------------------------------------------------------
extern "C" void kernel_launch(void* const* d_in, const int* in_sizes, int n_in,
                              void* d_out, int out_size, void* d_ws, size_t ws_size,
                              hipStream_t stream)
{
    const float* x  = (const float*)d_in[0];
    const float* h  = (const float*)d_in[1];
    const float* W1 = (const float*)d_in[2];
    const float* b1 = (const float*)d_in[3];
    const float* W2 = (const float*)d_in[4];
    const float* b2 = (const float*)d_in[5];
    const float* W3 = (const float*)d_in[6];
    const float* b3 = (const float*)d_in[7];
    const float* W4 = (const float*)d_in[8];
    const float* b4 = (const float*)d_in[9];
    float* out = (float*)d_out;

    umnn_fused<<<GRID, BLK, 0, stream>>>(x, h, W1, b1, W2, b2, W3, b3,
                                         W4, b4, out);
}

// Round 11
// 193.082 us; speedup vs baseline: 3.4277x; 3.4277x over previous
//
#include <hip/hip_runtime.h>
#include <hip/hip_bf16.h>
#include <math.h>

// ---------------------------------------------------------------------------
// Round 11: r7 base (best kernel: 131 us; nt=8 full-feature waves, zero
// per-tile barriers, Y1 software pipeline, deferred epilogue) + dynamic-VALU
// and serial-latency cuts. r10 lesson: launch_bounds(128,4) => VGPR 64 =>
// spill catastrophe (FETCH 1.7GB). r9 lesson: __builtin_elementwise packed
// math scalarizes — force v_pk_fma_f32 via inline asm instead.
//   1. v_pk_fma_f32 (inline asm) in Y1 build / layer-4 dot / hpart startup.
//   2. per-tile q-reduce shuffles removed: all 64 lanes ds_write_b32 their
//      layer-4 partial to vs[tt*64+lane]; q-sum moves to the final epilogue.
//   3. LDS: hshT unioned with vs (peak ~51 KB, 2 blocks/CU preserved).
// Numerics: identical rounding chain (absmax 0.125 vs thr 0.4725); only fp32
// sum order in layer-4/epilogue changes (~1e-6).
// ---------------------------------------------------------------------------

#define B_N    16384
#define KQ     51
#define HD     128
#define IND    64
#define BLK    128               // 2 waves
#define GRID   512
#define RPB    32                // b-rows per block
#define RPW    16                // b-rows per wave
#define SPW    (RPW * KQ)        // 816 samples per wave
#define TPW    (SPW / 16)        // 51 tiles per wave
#define HPITCH 36

typedef __attribute__((ext_vector_type(8))) short short8;
typedef __attribute__((ext_vector_type(4))) float f32x4;
typedef __attribute__((ext_vector_type(2))) float f32x2;

union S8U { short8 s8; unsigned u[4]; };

__device__ __forceinline__ f32x2 pk_fma(f32x2 a, f32x2 b, f32x2 c) {
    f32x2 d;
    asm("v_pk_fma_f32 %0, %1, %2, %3" : "=v"(d) : "v"(a), "v"(b), "v"(c));
    return d;
}

__device__ __forceinline__ unsigned short f2bf(float f) {
    __hip_bfloat16 t = __float2bfloat16(f);
    return *reinterpret_cast<unsigned short*>(&t);
}

#if defined(__gfx950__) && defined(__has_builtin)
#if __has_builtin(__builtin_amdgcn_cvt_pk_bf16_f32)
#define HAVE_PK_BF16 1
#endif
#endif

__device__ __forceinline__ unsigned pk_bf16(float lo, float hi) {
#ifdef HAVE_PK_BF16
    typedef __attribute__((ext_vector_type(2))) __bf16 bfv2;
    bfv2 r = __builtin_amdgcn_cvt_pk_bf16_f32(lo, hi);
    return *reinterpret_cast<unsigned*>(&r);
#else
    return (unsigned)f2bf(lo) | ((unsigned)f2bf(hi) << 16);
#endif
}

__launch_bounds__(BLK, 1)
__global__ void umnn_fused(const float* __restrict__ x,  const float* __restrict__ h,
                           const float* __restrict__ W1, const float* __restrict__ b1,
                           const float* __restrict__ W2, const float* __restrict__ b2,
                           const float* __restrict__ W3, const float* __restrict__ b3,
                           const float* __restrict__ W4, const float* __restrict__ b4,
                           float* __restrict__ out)
{
    __shared__ __align__(16) float hpL[RPB * HD];     // 16 KB block hpart
    __shared__ __align__(16) char  y2x[2][4096];      // 8 KB per-wave Y2 scratch
    __shared__ __align__(16) float uSh[2 * TPW * 64]; // 25.5 KB: hshT then vs
    __shared__ float xL[RPB];
    __shared__ float sSteps[KQ], sCcw[KQ];
    __shared__ float red2[2];

    float* hshT = uSh;                                // 63*36=2268 fl (pre-B2)

    const int tid  = threadIdx.x;
    const int w    = tid >> 6;
    const int lane = tid & 63;
    const int q    = lane >> 4;
    const int lm   = lane & 15;
    const int swz  = lm & 7;
    const int rowBase = blockIdx.x * RPB;

    // ---- CC tables (validated r4 formula) ----
    if (tid < KQ) {
        const int j = tid;
        const float pi50 = 0.06283185307179586f;
        sSteps[j] = __cosf((float)j * pi50);
        float s = 0.0f;
        for (int i = 0; i <= 50; i += 2) {
            float Wi = (i == 0) ? 1.0f : 2.0f / (1.0f - (float)(i * i));
            float lam;
            if (j == 0) lam = 0.5f;
            else {
                int mp = (i * j) % 100;
                lam = __cosf((float)mp * pi50);
                if (j == 50) lam *= 0.5f;
            }
            s += (lam * 0.04f) * Wi;
        }
        sCcw[j] = s;
    }
    // ---- xmax scan (x: 64 KB, cache-resident) ----
    {
        const f32x4* x4 = (const f32x4*)x;
        float mx = -1e30f;
        for (int i = tid; i < B_N / 4; i += BLK) {
            f32x4 v = x4[i];
            mx = fmaxf(fmaxf(mx, fmaxf(v[0], v[1])), fmaxf(v[2], v[3]));
        }
        #pragma unroll
        for (int d = 32; d > 0; d >>= 1) mx = fmaxf(mx, __shfl_xor(mx, d));
        if (lane == 0) red2[w] = mx;
    }
    // ---- stage h^T for this block's 32 rows; init xL ----
    for (int i = tid; i < RPB * 63; i += BLK) {
        int r = i / 63, d = i - r * 63;
        hshT[d * HPITCH + r] = h[rowBase * 63 + i];
    }
    if (tid < RPB) xL[tid] = x[rowBase + tid];
    __syncthreads();                                   // B1

    const float xmax = fmaxf(red2[0], red2[1]) + 10.0f;

    // ---- block hpart: thread tid = feature n, 32 rows, pk_fma pairs ----
    {
        const int n = tid;
        const float b1v = b1[n];
        f32x2 acc2[RPB / 2];
        #pragma unroll
        for (int r = 0; r < RPB / 2; ++r) acc2[r] = (f32x2){b1v, b1v};
        const float* wr = W1 + n * IND + 1;
        #pragma unroll 1
        for (int d = 0; d < IND - 1; ++d) {
            const float wv = wr[d];
            const f32x2 wv2 = {wv, wv};
            const float* ht = hshT + d * HPITCH;
            #pragma unroll
            for (int rc = 0; rc < RPB / 4; ++rc) {
                f32x4 hv = *(const f32x4*)(ht + rc * 4);
                acc2[rc * 2]     = pk_fma(wv2, (f32x2){hv[0], hv[1]}, acc2[rc * 2]);
                acc2[rc * 2 + 1] = pk_fma(wv2, (f32x2){hv[2], hv[3]}, acc2[rc * 2 + 1]);
            }
        }
        #pragma unroll
        for (int r = 0; r < RPB; ++r) hpL[r * HD + n] = acc2[r >> 1][r & 1];
    }

    // ---- wave-resident weights/biases (full 128 output features) ----
    f32x2 w1x2[16];
    #pragma unroll
    for (int kk = 0; kk < 4; ++kk)
        #pragma unroll
        for (int jj = 0; jj < 4; ++jj)
            w1x2[kk * 4 + jj] = (f32x2){W1[(kk * 32 + q * 8 + 2 * jj) * IND],
                                        W1[(kk * 32 + q * 8 + 2 * jj + 1) * IND]};

    short8 W2A[8][4], W3A[8][4];
    f32x4  b2c[8], b3c[8];
    f32x2  W4c2[16];
    #pragma unroll
    for (int nt = 0; nt < 8; ++nt) {
        #pragma unroll
        for (int kk = 0; kk < 4; ++kk) {
            const float* p2 = W2 + (nt * 16 + lm) * HD + kk * 32 + q * 8;
            const float* p3 = W3 + (nt * 16 + lm) * HD + kk * 32 + q * 8;
            S8U a2, a3;
            #pragma unroll
            for (int j = 0; j < 4; ++j) {
                a2.u[j] = pk_bf16(p2[2 * j], p2[2 * j + 1]);
                a3.u[j] = pk_bf16(p3[2 * j], p3[2 * j + 1]);
            }
            W2A[nt][kk] = a2.s8; W3A[nt][kk] = a3.s8;
        }
        b2c[nt] = *(const f32x4*)(b2 + nt * 16 + q * 4);
        b3c[nt] = *(const f32x4*)(b3 + nt * 16 + q * 4);
        W4c2[nt * 2]     = *(const f32x2*)(W4 + nt * 16 + q * 4);
        W4c2[nt * 2 + 1] = *(const f32x2*)(W4 + nt * 16 + q * 4 + 2);
    }
    const float b4v = b4[0];
    char*  myY2 = y2x[w];
    float* vsW  = uSh + w * (TPW * 64);                // vs (post-B2, hshT dead)

    // ---- precomputed Y2 LDS byte offsets (tile-invariant) ----
    int wOff[8], rOff[4];
    #pragma unroll
    for (int nt = 0; nt < 8; ++nt)
        wOff[nt] = lm * 256 + (((2 * nt + (q >> 1)) ^ swz) << 4) + ((q & 1) << 3);
    #pragma unroll
    for (int kk = 0; kk < 4; ++kk)
        rOff[kk] = lm * 256 + (((kk * 4 + q) ^ swz) << 4);
    __syncthreads();                                   // B2 (hpL ready)

    const int S0 = blockIdx.x * (RPB * KQ) + w * SPW;

    // Y1 builder (prefetch may overshoot by 1 tile; rl clamped, result unused)
    auto computeY1 = [&](int tt, short8* Y) {
        const int s   = S0 + tt * 16 + lm;
        const unsigned row = (unsigned)s / KQ;
        const int k   = s - (int)row * KQ;
        const int rl  = min((int)row - rowBase, RPB - 1);
        const float x0 = xL[rl];
        const float X  = fmaf((xmax - x0) * 0.5f, sSteps[k] + 1.0f, x0);
        const f32x2 X2 = {X, X};
        #pragma unroll
        for (int kk = 0; kk < 4; ++kk) {
            const float* hp = hpL + rl * HD + kk * 32 + q * 8;
            f32x4 ha = *(const f32x4*)hp;
            f32x4 hb = *(const f32x4*)(hp + 4);
            f32x2 t0 = pk_fma(X2, w1x2[kk * 4 + 0], (f32x2){ha[0], ha[1]});
            f32x2 t1 = pk_fma(X2, w1x2[kk * 4 + 1], (f32x2){ha[2], ha[3]});
            f32x2 t2 = pk_fma(X2, w1x2[kk * 4 + 2], (f32x2){hb[0], hb[1]});
            f32x2 t3 = pk_fma(X2, w1x2[kk * 4 + 3], (f32x2){hb[2], hb[3]});
            S8U u;
            u.u[0] = pk_bf16(fmaxf(t0[0], 0.f), fmaxf(t0[1], 0.f));
            u.u[1] = pk_bf16(fmaxf(t1[0], 0.f), fmaxf(t1[1], 0.f));
            u.u[2] = pk_bf16(fmaxf(t2[0], 0.f), fmaxf(t2[1], 0.f));
            u.u[3] = pk_bf16(fmaxf(t3[0], 0.f), fmaxf(t3[1], 0.f));
            Y[kk] = u.s8;
        }
    };

    short8 Y1c[4], Y1n[4];
    computeY1(0, Y1c);

    // ================= per-wave tile loop: NO barriers =================
    #pragma unroll 1
    for (int tt = 0; tt < TPW; ++tt) {
        // ---- layer 2: 32 MFMA ----
        f32x4 C[8];
        #pragma unroll
        for (int nt = 0; nt < 8; ++nt) C[nt] = b2c[nt];
        #pragma unroll
        for (int kk = 0; kk < 4; ++kk)
            #pragma unroll
            for (int nt = 0; nt < 8; ++nt)
                C[nt] = __builtin_amdgcn_mfma_f32_16x16x32_bf16(W2A[nt][kk], Y1c[kk], C[nt], 0, 0, 0);

        // ---- Y2 write (wave-private, no barrier) ----
        #pragma unroll
        for (int nt = 0; nt < 8; ++nt) {
            unsigned lo = pk_bf16(fmaxf(C[nt][0], 0.f), fmaxf(C[nt][1], 0.f));
            unsigned hi = pk_bf16(fmaxf(C[nt][2], 0.f), fmaxf(C[nt][3], 0.f));
            *(int2*)(myY2 + wOff[nt]) = make_int2((int)lo, (int)hi);
        }

        // ---- pipeline: next tile's Y1 ----
        computeY1(tt + 1, Y1n);

        // ---- Y2 read ----
        short8 Y2[4];
        #pragma unroll
        for (int kk = 0; kk < 4; ++kk)
            Y2[kk] = *(const short8*)(myY2 + rOff[kk]);

        // ---- layer 3: 32 MFMA ----
        #pragma unroll
        for (int nt = 0; nt < 8; ++nt) C[nt] = b3c[nt];
        #pragma unroll
        for (int kk = 0; kk < 4; ++kk)
            #pragma unroll
            for (int nt = 0; nt < 8; ++nt)
                C[nt] = __builtin_amdgcn_mfma_f32_16x16x32_bf16(W3A[nt][kk], Y2[kk], C[nt], 0, 0, 0);

        // ---- layer 4 partial (pk_fma dot), per-lane store, NO shuffles ----
        f32x2 acc = {0.f, 0.f};
        #pragma unroll
        for (int nt = 0; nt < 8; ++nt) {
            f32x2 m0, m1;
            m0[0] = fmaxf(C[nt][0], 0.f); m0[1] = fmaxf(C[nt][1], 0.f);
            m1[0] = fmaxf(C[nt][2], 0.f); m1[1] = fmaxf(C[nt][3], 0.f);
            acc = pk_fma(m0, W4c2[nt * 2],     acc);
            acc = pk_fma(m1, W4c2[nt * 2 + 1], acc);
        }
        vsW[(tt << 6) + lane] = acc[0] + acc[1];

        #pragma unroll
        for (int kk = 0; kk < 4; ++kk) Y1c[kk] = Y1n[kk];
    }

    // ---- deferred epilogue (wave-private): q-sum + elu + ccw + row-reduce ----
    {
        const int r   = lane >> 2;          // wave-local row 0..15
        const int sub = lane & 3;
        float a = 0.f;
        #pragma unroll 1
        for (int j = 0; j < 13; ++j) {
            int kq = sub + 4 * j;
            if (kq < KQ) {
                int sl   = r * KQ + kq;
                int base = ((sl >> 4) << 6) + (sl & 15);
                float y4 = vsW[base] + vsW[base + 16] + vsW[base + 32]
                         + vsW[base + 48] + b4v;
                float f  = (y4 > 0.f) ? (y4 + 1.f) : __expf(y4);
                a = fmaf(f, sCcw[kq], a);
            }
        }
        a += __shfl_xor(a, 1);
        a += __shfl_xor(a, 2);
        if (sub == 0) {
            int rl = w * RPW + r;
            out[rowBase + rl] = a * (xmax - xL[rl]) * 0.5f;
        }
    }
}

// ---------------------------------------------------------------------------
extern "C" void kernel_launch(void* const* d_in, const int* in_sizes, int n_in,
                              void* d_out, int out_size, void* d_ws, size_t ws_size,
                              hipStream_t stream)
{
    const float* x  = (const float*)d_in[0];
    const float* h  = (const float*)d_in[1];
    const float* W1 = (const float*)d_in[2];
    const float* b1 = (const float*)d_in[3];
    const float* W2 = (const float*)d_in[4];
    const float* b2 = (const float*)d_in[5];
    const float* W3 = (const float*)d_in[6];
    const float* b3 = (const float*)d_in[7];
    const float* W4 = (const float*)d_in[8];
    const float* b4 = (const float*)d_in[9];
    float* out = (float*)d_out;

    umnn_fused<<<GRID, BLK, 0, stream>>>(x, h, W1, b1, W2, b2, W3, b3,
                                         W4, b4, out);
}